// Round 4
// baseline (287.884 us; speedup 1.0000x reference)
//
#include <hip/hip_runtime.h>
#include <math.h>

#define BATCH 16384
#define CTX 10
#define NEG 5
#define DIM 128
#define WAVES_PER_BLOCK 4
#define NBLOCKS (BATCH / WAVES_PER_BLOCK)   // 4096

// logsigmoid(x) = min(x,0) - log1p(exp(-|x|))   (numerically stable)
__device__ __forceinline__ float logsig(float x) {
    return fminf(x, 0.f) - log1pf(expf(-fabsf(x)));
}

__global__ __launch_bounds__(256) void cbow_fused(
    const int* __restrict__ pos_u,      // [B, CTX]
    const int* __restrict__ pos_w,      // [B]
    const int* __restrict__ neg_w,      // [B, NEG]
    const float* __restrict__ u_weight, // [VOCAB, DIM]
    const float* __restrict__ w_weight, // [VOCAB, DIM]
    float* __restrict__ partials,       // [NBLOCKS]
    unsigned int* __restrict__ counter, // [1], pre-zeroed
    float* __restrict__ out)            // [1]
{
    const int tid  = threadIdx.x;
    const int wave = tid >> 6;          // 0..3: which b within block
    const int lane = tid & 63;          // 2 dims per lane (float2)
    const int b    = blockIdx.x * WAVES_PER_BLOCK + wave;

    // --- lane-parallel index fetch (3 masked loads) ---
    // lanes 0..9 -> ctx, lane 10 -> pos_w, lanes 11..15 -> neg_w
    int myidx = 0;
    if (lane < CTX)                 myidx = pos_u[b * CTX + lane];
    else if (lane == CTX)           myidx = pos_w[b];
    else if (lane < CTX + 1 + NEG)  myidx = neg_w[b * NEG + (lane - CTX - 1)];

    // --- gather 16 rows; indices hoisted to SGPRs so address math is scalar ---
    float2 su = make_float2(0.f, 0.f);  // context sum (this lane's 2 dims)
    float2 wn = make_float2(0.f, 0.f);  // sum of NEG rows
    float2 wp = make_float2(0.f, 0.f);  // positive row
    const int col = lane * 2;
#pragma unroll
    for (int i = 0; i < 16; ++i) {
        const int idx = __builtin_amdgcn_readfirstlane(__shfl(myidx, i, 64));
        const float* base = ((i < CTX) ? u_weight : w_weight) + (size_t)idx * DIM;
        const float2 v = *reinterpret_cast<const float2*>(base + col);
        if (i < CTX)       { su.x += v.x; su.y += v.y; }
        else if (i == CTX) { wp = v; }
        else               { wn.x += v.x; wn.y += v.y; }
    }

    float s_pos = su.x * wp.x + su.y * wp.y;
    float s_neg = su.x * wn.x + su.y * wn.y;

    // --- full-wave (64 lane) reduction of both dots ---
#pragma unroll
    for (int m = 32; m >= 1; m >>= 1) {
        s_pos += __shfl_xor(s_pos, m, 64);
        s_neg += __shfl_xor(s_neg, m, 64);
    }

    // --- per-block partial ---
    __shared__ float acc[WAVES_PER_BLOCK];
    if (lane == 0) acc[wave] = logsig(s_pos) + logsig(-s_neg);
    __syncthreads();

    __shared__ int is_last;
    if (tid == 0) {
        partials[blockIdx.x] = acc[0] + acc[1] + acc[2] + acc[3];
        __threadfence();                       // make partial visible device-wide
        unsigned int old = atomicAdd(counter, 1u);
        is_last = (old == (unsigned int)(gridDim.x - 1));
    }
    __syncthreads();

    // --- last-arriving block reduces all partials and writes the result ---
    if (is_last) {
        float s = 0.f;
        for (int i = tid; i < NBLOCKS; i += 256)
            s += __hip_atomic_load(&partials[i], __ATOMIC_ACQUIRE,
                                   __HIP_MEMORY_SCOPE_AGENT);
#pragma unroll
        for (int m = 32; m >= 1; m >>= 1) s += __shfl_xor(s, m, 64);
        __shared__ float ws[4];
        if ((tid & 63) == 0) ws[tid >> 6] = s;
        __syncthreads();
        if (tid == 0) out[0] = -(ws[0] + ws[1] + ws[2] + ws[3]);  // -loss
    }
}

extern "C" void kernel_launch(void* const* d_in, const int* in_sizes, int n_in,
                              void* d_out, int out_size, void* d_ws, size_t ws_size,
                              hipStream_t stream) {
    const int*   pos_u    = (const int*)d_in[0];
    const int*   pos_w    = (const int*)d_in[1];
    const int*   neg_w    = (const int*)d_in[2];
    const float* u_weight = (const float*)d_in[3];
    const float* w_weight = (const float*)d_in[4];
    float*       out      = (float*)d_out;

    unsigned int* counter  = (unsigned int*)d_ws;                  // 4 B
    float*        partials = (float*)((char*)d_ws + 128);          // NBLOCKS floats

    hipMemsetAsync(counter, 0, sizeof(unsigned int), stream);
    cbow_fused<<<NBLOCKS, 256, 0, stream>>>(pos_u, pos_w, neg_w,
                                            u_weight, w_weight,
                                            partials, counter, out);
}

// Round 5
// 126.298 us; speedup vs baseline: 2.2794x; 2.2794x over previous
//
#include <hip/hip_runtime.h>
#include <math.h>

#define BATCH 16384
#define CTX 10
#define NEG 5
#define DIM 128
#define B_PER_BLOCK 8
#define NBLOCKS (BATCH / B_PER_BLOCK)   // 2048

// logsigmoid(x) = min(x,0) - log1p(exp(-|x|))   (numerically stable)
__device__ __forceinline__ float logsig(float x) {
    return fminf(x, 0.f) - log1pf(expf(-fabsf(x)));
}

__global__ __launch_bounds__(256) void cbow_partial(
    const int* __restrict__ pos_u,      // [B, CTX]
    const int* __restrict__ pos_w,      // [B]
    const int* __restrict__ neg_w,      // [B, NEG]
    const float* __restrict__ u_weight, // [VOCAB, DIM]
    const float* __restrict__ w_weight, // [VOCAB, DIM]
    float* __restrict__ partials)       // [NBLOCKS]
{
    const int tid   = threadIdx.x;
    const int group = tid >> 5;         // 0..7: which b within block
    const int lane  = tid & 31;         // 0..31: 4 dims each
    const int b     = blockIdx.x * B_PER_BLOCK + group;
    const int col   = lane * 4;

    // --- lane-parallel index fetch: 3 masked loads instead of 16 broadcast loads ---
    // lanes 0..9 -> ctx indices, lane 10 -> pos_w, lanes 11..15 -> neg_w
    int myidx = 0;
    if (lane < CTX)                 myidx = pos_u[b * CTX + lane];
    else if (lane == CTX)           myidx = pos_w[b];
    else if (lane < CTX + 1 + NEG)  myidx = neg_w[b * NEG + (lane - CTX - 1)];

    // broadcast: all 16 indices resident before any gather issues
    int idx[16];
#pragma unroll
    for (int i = 0; i < 16; ++i) idx[i] = __shfl(myidx, i, 32);

    // --- context sum: two independent chains to halve dependency depth ---
    float4 sa = make_float4(0.f, 0.f, 0.f, 0.f);
    float4 sb = make_float4(0.f, 0.f, 0.f, 0.f);
#pragma unroll
    for (int c = 0; c < CTX; c += 2) {
        const float4 va = *reinterpret_cast<const float4*>(
            u_weight + (size_t)idx[c] * DIM + col);
        const float4 vb = *reinterpret_cast<const float4*>(
            u_weight + (size_t)idx[c + 1] * DIM + col);
        sa.x += va.x; sa.y += va.y; sa.z += va.z; sa.w += va.w;
        sb.x += vb.x; sb.y += vb.y; sb.z += vb.z; sb.w += vb.w;
    }
    float4 su = make_float4(sa.x + sb.x, sa.y + sb.y, sa.z + sb.z, sa.w + sb.w);

    // --- negatives: two chains (reference sums over NEG before logsig) ---
    float4 na = make_float4(0.f, 0.f, 0.f, 0.f);
    float4 nb = make_float4(0.f, 0.f, 0.f, 0.f);
#pragma unroll
    for (int k = 0; k < NEG - 1; k += 2) {
        const float4 va = *reinterpret_cast<const float4*>(
            w_weight + (size_t)idx[CTX + 1 + k] * DIM + col);
        const float4 vb = *reinterpret_cast<const float4*>(
            w_weight + (size_t)idx[CTX + 2 + k] * DIM + col);
        na.x += va.x; na.y += va.y; na.z += va.z; na.w += va.w;
        nb.x += vb.x; nb.y += vb.y; nb.z += vb.z; nb.w += vb.w;
    }
    {
        const float4 v = *reinterpret_cast<const float4*>(
            w_weight + (size_t)idx[CTX + NEG] * DIM + col);
        na.x += v.x; na.y += v.y; na.z += v.z; na.w += v.w;
    }
    float4 wn = make_float4(na.x + nb.x, na.y + nb.y, na.z + nb.z, na.w + nb.w);

    // --- positive row ---
    const float4 wp = *reinterpret_cast<const float4*>(
        w_weight + (size_t)idx[CTX] * DIM + col);

    float s_pos = su.x * wp.x + su.y * wp.y + su.z * wp.z + su.w * wp.w;
    float s_neg = su.x * wn.x + su.y * wn.y + su.z * wn.z + su.w * wn.w;

    // --- reduce across the 32-lane group (xor masks <=16 stay in-group) ---
#pragma unroll
    for (int m = 16; m >= 1; m >>= 1) {
        s_pos += __shfl_xor(s_pos, m, 64);
        s_neg += __shfl_xor(s_neg, m, 64);
    }

    // --- per-block accumulation: plain indexed store, tid 0 sums ---
    __shared__ float acc[B_PER_BLOCK];
    if (lane == 0) acc[group] = logsig(s_pos) + logsig(-s_neg);
    __syncthreads();
    if (tid == 0) {
        float t = 0.f;
#pragma unroll
        for (int g = 0; g < B_PER_BLOCK; ++g) t += acc[g];
        partials[blockIdx.x] = t;
    }
}

__global__ __launch_bounds__(256) void cbow_reduce(
    const float* __restrict__ partials, // [NBLOCKS]
    float* __restrict__ out)
{
    const int tid = threadIdx.x;
    float s = 0.f;
    for (int i = tid; i < NBLOCKS; i += 256) s += partials[i];
#pragma unroll
    for (int m = 32; m >= 1; m >>= 1) s += __shfl_xor(s, m, 64);
    __shared__ float ws[4];
    if ((tid & 63) == 0) ws[tid >> 6] = s;
    __syncthreads();
    if (tid == 0) {
        float tot = ws[0] + ws[1] + ws[2] + ws[3];
        out[0] = -tot;   // reference returns -loss
    }
}

extern "C" void kernel_launch(void* const* d_in, const int* in_sizes, int n_in,
                              void* d_out, int out_size, void* d_ws, size_t ws_size,
                              hipStream_t stream) {
    const int*   pos_u    = (const int*)d_in[0];
    const int*   pos_w    = (const int*)d_in[1];
    const int*   neg_w    = (const int*)d_in[2];
    const float* u_weight = (const float*)d_in[3];
    const float* w_weight = (const float*)d_in[4];
    float*       out      = (float*)d_out;
    float*       partials = (float*)d_ws;   // NBLOCKS floats

    cbow_partial<<<NBLOCKS, 256, 0, stream>>>(pos_u, pos_w, neg_w,
                                              u_weight, w_weight, partials);
    cbow_reduce<<<1, 256, 0, stream>>>(partials, out);
}